// Round 1
// baseline (93.419 us; speedup 1.0000x reference)
//
#include <hip/hip_runtime.h>

// QCQP quaternion loss: per-element 4x4 symmetric eigensolve (smallest
// eigenvector) via fully-unrolled cyclic Jacobi in registers, then
// sign-invariant distance loss, mean-reduced.

__global__ __launch_bounds__(256) void qcqp_loss_kernel(
    const float* __restrict__ A_vec, const float* __restrict__ q_t,
    float* __restrict__ acc, int B)
{
    int i = blockIdx.x * blockDim.x + threadIdx.x;
    float loss = 0.f;
    if (i < B) {
        // ---- load 10 coefficients (row-major upper triangle), negate ----
        const float* av = A_vec + (size_t)i * 10;   // 40*i bytes -> 8B aligned
        float2 v01 = *(const float2*)(av + 0);
        float2 v23 = *(const float2*)(av + 2);
        float2 v45 = *(const float2*)(av + 4);
        float2 v67 = *(const float2*)(av + 6);
        float2 v89 = *(const float2*)(av + 8);

        float a[4][4];
        a[0][0] = -v01.x; a[0][1] = -v01.y; a[0][2] = -v23.x; a[0][3] = -v23.y;
        a[1][1] = -v45.x; a[1][2] = -v45.y; a[1][3] = -v67.x;
        a[2][2] = -v67.y; a[2][3] = -v89.x; a[3][3] = -v89.y;
        a[1][0] = a[0][1]; a[2][0] = a[0][2]; a[3][0] = a[0][3];
        a[2][1] = a[1][2]; a[3][1] = a[1][3]; a[3][2] = a[2][3];

        float V[4][4] = {{1,0,0,0},{0,1,0,0},{0,0,1,0},{0,0,0,1}};

        // ---- cyclic Jacobi, 6 sweeps, fully unrolled (all static idx) ----
        const int PP[6] = {0,0,0,1,1,2};
        const int QQ[6] = {1,2,3,2,3,3};
        #pragma unroll
        for (int sweep = 0; sweep < 6; ++sweep) {
            #pragma unroll
            for (int r = 0; r < 6; ++r) {
                const int p = PP[r], q = QQ[r];
                float apq = a[p][q];
                float app = a[p][p], aqq = a[q][q];
                float t;
                if (apq != 0.f) {
                    float theta = (aqq - app) / (2.f * apq);
                    t = 1.f / (fabsf(theta) + sqrtf(theta * theta + 1.f));
                    t = (theta < 0.f) ? -t : t;
                } else {
                    t = 0.f;
                }
                float c = 1.f / sqrtf(1.f + t * t);
                float s = t * c;
                a[p][p] = app - t * apq;
                a[q][q] = aqq + t * apq;
                a[p][q] = 0.f; a[q][p] = 0.f;
                #pragma unroll
                for (int k = 0; k < 4; ++k) {
                    if (k != p && k != q) {
                        float akp = a[k][p], akq = a[k][q];
                        float np_ = c * akp - s * akq;
                        float nq_ = s * akp + c * akq;
                        a[k][p] = np_; a[p][k] = np_;
                        a[k][q] = nq_; a[q][k] = nq_;
                    }
                    float vkp = V[k][p], vkq = V[k][q];
                    V[k][p] = c * vkp - s * vkq;
                    V[k][q] = s * vkp + c * vkq;
                }
            }
        }

        // ---- select eigenvector of smallest eigenvalue (static idx only) --
        float ev = a[0][0];
        float q0 = V[0][0], q1 = V[1][0], q2 = V[2][0], q3 = V[3][0];
        #pragma unroll
        for (int j = 1; j < 4; ++j) {
            bool b = a[j][j] < ev;
            ev = b ? a[j][j] : ev;
            q0 = b ? V[0][j] : q0;
            q1 = b ? V[1][j] : q1;
            q2 = b ? V[2][j] : q2;
            q3 = b ? V[3][j] : q3;
        }

        // ---- loss ----
        float4 qt = *(const float4*)(q_t + (size_t)i * 4);
        float dm = (q0 - qt.x) * (q0 - qt.x) + (q1 - qt.y) * (q1 - qt.y)
                 + (q2 - qt.z) * (q2 - qt.z) + (q3 - qt.w) * (q3 - qt.w);
        float dp = (q0 + qt.x) * (q0 + qt.x) + (q1 + qt.y) * (q1 + qt.y)
                 + (q2 + qt.z) * (q2 + qt.z) + (q3 + qt.w) * (q3 + qt.w);
        float d2 = fminf(dm, dp);
        loss = 2.f * d2 * (4.f - d2);
    }

    // ---- block reduction: wave64 shuffle -> LDS -> one atomic per block ---
    #pragma unroll
    for (int off = 32; off > 0; off >>= 1)
        loss += __shfl_down(loss, off, 64);
    __shared__ float sm[4];
    int lane = threadIdx.x & 63, wid = threadIdx.x >> 6;
    if (lane == 0) sm[wid] = loss;
    __syncthreads();
    if (threadIdx.x == 0) {
        atomicAdd(acc, sm[0] + sm[1] + sm[2] + sm[3]);
    }
}

__global__ void qcqp_finalize_kernel(const float* __restrict__ acc,
                                     float* __restrict__ out, int B)
{
    out[0] = acc[0] / (float)B;
}

extern "C" void kernel_launch(void* const* d_in, const int* in_sizes, int n_in,
                              void* d_out, int out_size, void* d_ws, size_t ws_size,
                              hipStream_t stream)
{
    const float* A_vec = (const float*)d_in[0];
    const float* q_t   = (const float*)d_in[1];
    int B = in_sizes[0] / 10;
    float* acc = (float*)d_ws;

    hipMemsetAsync(acc, 0, sizeof(float), stream);
    int blocks = (B + 255) / 256;
    qcqp_loss_kernel<<<blocks, 256, 0, stream>>>(A_vec, q_t, acc, B);
    qcqp_finalize_kernel<<<1, 1, 0, stream>>>(acc, (float*)d_out, B);
}

// Round 2
// 67.379 us; speedup vs baseline: 1.3865x; 1.3865x over previous
//
#include <hip/hip_runtime.h>

// QCQP quaternion loss. Per element: smallest eigenpair of 4x4 symmetric A
// via characteristic polynomial + monotone Newton from the Gershgorin lower
// bound (QUEST-style), eigenvector as 4D cross product of 3 rows of A-lam*I
// (adjugate column), max-norm candidate selected. Loss = 8(1 - <v,qt>^2/|v|^2)
// (exact rewrite of min-distance loss for unit quaternions). Mean-reduce.

__device__ __forceinline__ void cross4(const float* x, const float* y,
                                       const float* z, float* w) {
    // w = generalized cross product: w . x = w . y = w . z = 0,
    // det[a;x;y;z] = a . w
    float m01 = y[0]*z[1] - y[1]*z[0];
    float m02 = y[0]*z[2] - y[2]*z[0];
    float m03 = y[0]*z[3] - y[3]*z[0];
    float m12 = y[1]*z[2] - y[2]*z[1];
    float m13 = y[1]*z[3] - y[3]*z[1];
    float m23 = y[2]*z[3] - y[3]*z[2];
    w[0] =  (x[1]*m23 - x[2]*m13 + x[3]*m12);
    w[1] = -(x[0]*m23 - x[2]*m03 + x[3]*m02);
    w[2] =  (x[0]*m13 - x[1]*m03 + x[3]*m01);
    w[3] = -(x[0]*m12 - x[1]*m02 + x[2]*m01);
}

__device__ __forceinline__ float det3s(float p, float q, float r,
                                       float s, float t, float u) {
    // det [[p,q,r],[q,s,t],[r,t,u]]
    return p*(s*u - t*t) - q*(q*u - r*t) + r*(q*t - r*s);
}

__global__ __launch_bounds__(256) void qcqp_loss_kernel(
    const float* __restrict__ A_vec, const float* __restrict__ q_t,
    float* __restrict__ acc, int B)
{
    int i = blockIdx.x * blockDim.x + threadIdx.x;
    float loss = 0.f;
    if (i < B) {
        const float* av = A_vec + (size_t)i * 10;   // 40B stride -> 8B aligned
        float2 v01 = *(const float2*)(av + 0);
        float2 v23 = *(const float2*)(av + 2);
        float2 v45 = *(const float2*)(av + 4);
        float2 v67 = *(const float2*)(av + 6);
        float2 v89 = *(const float2*)(av + 8);

        // A = -sym(A_vec)
        float m00 = -v01.x, m01 = -v01.y, m02 = -v23.x, m03 = -v23.y;
        float m11 = -v45.x, m12 = -v45.y, m13 = -v67.x;
        float m22 = -v67.y, m23 = -v89.x, m33 = -v89.y;

        // ---- characteristic polynomial p(l) = l^4 - e1 l^3 + e2 l^2 - e3 l + e4
        float e1 = m00 + m11 + m22 + m33;
        float e2 = m00*m11 - m01*m01 + m00*m22 - m02*m02 + m00*m33 - m03*m03
                 + m11*m22 - m12*m12 + m11*m33 - m13*m13 + m22*m33 - m23*m23;
        float e3 = det3s(m11, m12, m13, m22, m23, m33)    // delete row/col 0
                 + det3s(m00, m02, m03, m22, m23, m33)    // delete 1
                 + det3s(m00, m01, m03, m11, m13, m33)    // delete 2
                 + det3s(m00, m01, m02, m11, m12, m22);   // delete 3
        float r0[4] = {m00, m01, m02, m03};
        float r1[4] = {m01, m11, m12, m13};
        float r2[4] = {m02, m12, m22, m23};
        float r3[4] = {m03, m13, m23, m33};
        float cw[4];
        cross4(r1, r2, r3, cw);
        float e4 = r0[0]*cw[0] + r0[1]*cw[1] + r0[2]*cw[2] + r0[3]*cw[3];

        // ---- Newton from Gershgorin lower bound (monotone to lambda_min) ----
        float s0 = fabsf(m01) + fabsf(m02) + fabsf(m03);
        float s1 = fabsf(m01) + fabsf(m12) + fabsf(m13);
        float s2 = fabsf(m02) + fabsf(m12) + fabsf(m23);
        float s3 = fabsf(m03) + fabsf(m13) + fabsf(m23);
        float lo = fminf(fminf(m00 - s0, m11 - s1), fminf(m22 - s2, m33 - s3)) - 1e-3f;
        float hi = fminf(fminf(m00, m11), fminf(m22, m33));  // lam_min <= min diag
        float lam = lo;
        #pragma unroll
        for (int it = 0; it < 12; ++it) {
            float p  = (((lam - e1)*lam + e2)*lam - e3)*lam + e4;
            float dp = ((4.f*lam - 3.f*e1)*lam + 2.f*e2)*lam - e3;
            dp = fminf(dp, -1e-12f);          // p' < 0 below lambda_min; clamp
            lam = lam - p * __builtin_amdgcn_rcpf(dp);
            lam = fminf(fmaxf(lam, lo), hi);  // keep finite & in bracket
        }

        // ---- eigenvector: null space of M = A - lam I via 4D cross products
        float R0[4] = {m00 - lam, m01, m02, m03};
        float R1[4] = {m01, m11 - lam, m12, m13};
        float R2[4] = {m02, m12, m22 - lam, m23};
        float R3[4] = {m03, m13, m23, m33 - lam};
        float c0[4], c1[4], c2[4], c3[4];
        cross4(R1, R2, R3, c0);   // candidate excluding row 0
        cross4(R0, R2, R3, c1);
        cross4(R0, R1, R3, c2);
        cross4(R0, R1, R2, c3);
        float n0 = c0[0]*c0[0] + c0[1]*c0[1] + c0[2]*c0[2] + c0[3]*c0[3];
        float n1 = c1[0]*c1[0] + c1[1]*c1[1] + c1[2]*c1[2] + c1[3]*c1[3];
        float n2_ = c2[0]*c2[0] + c2[1]*c2[1] + c2[2]*c2[2] + c2[3]*c2[3];
        float n3 = c3[0]*c3[0] + c3[1]*c3[1] + c3[2]*c3[2] + c3[3]*c3[3];

        float bn = n0, w0 = c0[0], w1 = c0[1], w2 = c0[2], w3 = c0[3];
        bool b;
        b = n1 > bn; bn = b ? n1 : bn; w0 = b ? c1[0] : w0; w1 = b ? c1[1] : w1;
                     w2 = b ? c1[2] : w2; w3 = b ? c1[3] : w3;
        b = n2_ > bn; bn = b ? n2_ : bn; w0 = b ? c2[0] : w0; w1 = b ? c2[1] : w1;
                     w2 = b ? c2[2] : w2; w3 = b ? c2[3] : w3;
        b = n3 > bn; bn = b ? n3 : bn; w0 = b ? c3[0] : w0; w1 = b ? c3[1] : w1;
                     w2 = b ? c3[2] : w2; w3 = b ? c3[3] : w3;

        // ---- loss = 8(1 - <v,qt>^2/|v|^2), exact for unit quaternions ----
        float4 qt = *(const float4*)(q_t + (size_t)i * 4);
        float d = w0*qt.x + w1*qt.y + w2*qt.z + w3*qt.w;
        float inv = __builtin_amdgcn_rcpf(fmaxf(bn, 1e-20f));
        loss = 8.f * (bn - d*d) * inv;
        loss = fminf(fmaxf(loss, 0.f), 8.f);  // bound + NaN-sanitize
    }

    // ---- block reduction: wave64 shuffle -> LDS -> one atomic per block ---
    #pragma unroll
    for (int off = 32; off > 0; off >>= 1)
        loss += __shfl_down(loss, off, 64);
    __shared__ float sm[4];
    int lane = threadIdx.x & 63, wid = threadIdx.x >> 6;
    if (lane == 0) sm[wid] = loss;
    __syncthreads();
    if (threadIdx.x == 0) {
        atomicAdd(acc, sm[0] + sm[1] + sm[2] + sm[3]);
    }
}

__global__ void qcqp_finalize_kernel(const float* __restrict__ acc,
                                     float* __restrict__ out, int B)
{
    out[0] = acc[0] / (float)B;
}

extern "C" void kernel_launch(void* const* d_in, const int* in_sizes, int n_in,
                              void* d_out, int out_size, void* d_ws, size_t ws_size,
                              hipStream_t stream)
{
    const float* A_vec = (const float*)d_in[0];
    const float* q_t   = (const float*)d_in[1];
    int B = in_sizes[0] / 10;
    float* acc = (float*)d_ws;

    hipMemsetAsync(acc, 0, sizeof(float), stream);
    int blocks = (B + 255) / 256;
    qcqp_loss_kernel<<<blocks, 256, 0, stream>>>(A_vec, q_t, acc, B);
    qcqp_finalize_kernel<<<1, 1, 0, stream>>>(acc, (float*)d_out, B);
}

// Round 3
// 47.154 us; speedup vs baseline: 1.9811x; 1.4289x over previous
//
#include <hip/hip_runtime.h>

// QCQP quaternion loss. Per element: smallest eigenpair of 4x4 symmetric A
// via characteristic polynomial + monotone Newton from the Gershgorin lower
// bound, eigenvector = 4D cross product of 3 rows of A-lam*I (adjugate
// column, max-norm candidate). Loss = 8(1 - <v,qt>^2/|v|^2). Mean-reduce.
//
// R2: ILP=4 (four elements/thread, Newton chains explicitly interleaved to
// hide the ~40cy/iter dependency latency that left VALUBusy at 17%), and
// finalize fused via device-scope completion counter (one fewer dispatch).

#define ILP 4

__device__ __forceinline__ void cross4(const float* x, const float* y,
                                       const float* z, float* w) {
    float m01 = y[0]*z[1] - y[1]*z[0];
    float m02 = y[0]*z[2] - y[2]*z[0];
    float m03 = y[0]*z[3] - y[3]*z[0];
    float m12 = y[1]*z[2] - y[2]*z[1];
    float m13 = y[1]*z[3] - y[3]*z[1];
    float m23 = y[2]*z[3] - y[3]*z[2];
    w[0] =  (x[1]*m23 - x[2]*m13 + x[3]*m12);
    w[1] = -(x[0]*m23 - x[2]*m03 + x[3]*m02);
    w[2] =  (x[0]*m13 - x[1]*m03 + x[3]*m01);
    w[3] = -(x[0]*m12 - x[1]*m02 + x[2]*m01);
}

__device__ __forceinline__ float det3s(float p, float q, float r,
                                       float s, float t, float u) {
    return p*(s*u - t*t) - q*(q*u - r*t) + r*(q*t - r*s);
}

__global__ __launch_bounds__(256) void qcqp_loss_kernel(
    const float* __restrict__ A_vec, const float* __restrict__ q_t,
    float* __restrict__ acc, unsigned int* __restrict__ cnt,
    float* __restrict__ out, int B, int nthreads, int nblocks)
{
    int tid = blockIdx.x * blockDim.x + threadIdx.x;

    // per-element state, index k always compile-time (unrolled loops)
    float m[ILP][10];
    float e1[ILP], e2[ILP], e3[ILP], e4[ILP];
    float lo[ILP], hi[ILP], lam[ILP];
    bool  act[ILP];

    // ---- phase 1: load + characteristic polynomial coefficients ----
    #pragma unroll
    for (int k = 0; k < ILP; ++k) {
        int i = tid + k * nthreads;
        act[k] = (i < B);
        int is = act[k] ? i : 0;
        const float* av = A_vec + (size_t)is * 10;
        float2 v01 = *(const float2*)(av + 0);
        float2 v23 = *(const float2*)(av + 2);
        float2 v45 = *(const float2*)(av + 4);
        float2 v67 = *(const float2*)(av + 6);
        float2 v89 = *(const float2*)(av + 8);
        float m00 = -v01.x, m01 = -v01.y, m02 = -v23.x, m03 = -v23.y;
        float m11 = -v45.x, m12 = -v45.y, m13 = -v67.x;
        float m22 = -v67.y, m23 = -v89.x, m33 = -v89.y;
        m[k][0]=m00; m[k][1]=m01; m[k][2]=m02; m[k][3]=m03; m[k][4]=m11;
        m[k][5]=m12; m[k][6]=m13; m[k][7]=m22; m[k][8]=m23; m[k][9]=m33;

        e1[k] = m00 + m11 + m22 + m33;
        e2[k] = m00*m11 - m01*m01 + m00*m22 - m02*m02 + m00*m33 - m03*m03
              + m11*m22 - m12*m12 + m11*m33 - m13*m13 + m22*m33 - m23*m23;
        e3[k] = det3s(m11, m12, m13, m22, m23, m33)
              + det3s(m00, m02, m03, m22, m23, m33)
              + det3s(m00, m01, m03, m11, m13, m33)
              + det3s(m00, m01, m02, m11, m12, m22);
        float r0[4] = {m00, m01, m02, m03};
        float r1[4] = {m01, m11, m12, m13};
        float r2[4] = {m02, m12, m22, m23};
        float r3[4] = {m03, m13, m23, m33};
        float cw[4];
        cross4(r1, r2, r3, cw);
        e4[k] = r0[0]*cw[0] + r0[1]*cw[1] + r0[2]*cw[2] + r0[3]*cw[3];

        float s0 = fabsf(m01) + fabsf(m02) + fabsf(m03);
        float s1 = fabsf(m01) + fabsf(m12) + fabsf(m13);
        float s2 = fabsf(m02) + fabsf(m12) + fabsf(m23);
        float s3 = fabsf(m03) + fabsf(m13) + fabsf(m23);
        lo[k] = fminf(fminf(m00 - s0, m11 - s1), fminf(m22 - s2, m33 - s3)) - 1e-3f;
        hi[k] = fminf(fminf(m00, m11), fminf(m22, m33));
        lam[k] = lo[k];
    }

    // ---- phase 2: Newton, ILP chains interleaved (this is the point) ----
    #pragma unroll
    for (int it = 0; it < 12; ++it) {
        #pragma unroll
        for (int k = 0; k < ILP; ++k) {
            float l = lam[k];
            float p  = (((l - e1[k])*l + e2[k])*l - e3[k])*l + e4[k];
            float dp = ((4.f*l - 3.f*e1[k])*l + 2.f*e2[k])*l - e3[k];
            dp = fminf(dp, -1e-12f);
            l = l - p * __builtin_amdgcn_rcpf(dp);
            lam[k] = fminf(fmaxf(l, lo[k]), hi[k]);
        }
    }

    // ---- phase 3: eigenvector + loss, per element (caps reg pressure) ----
    float lsum = 0.f;
    #pragma unroll
    for (int k = 0; k < ILP; ++k) {
        float m00=m[k][0], m01=m[k][1], m02=m[k][2], m03=m[k][3], m11=m[k][4];
        float m12=m[k][5], m13=m[k][6], m22=m[k][7], m23=m[k][8], m33=m[k][9];
        float l = lam[k];
        float R0[4] = {m00 - l, m01, m02, m03};
        float R1[4] = {m01, m11 - l, m12, m13};
        float R2[4] = {m02, m12, m22 - l, m23};
        float R3[4] = {m03, m13, m23, m33 - l};
        float c0[4], c1[4], c2[4], c3[4];
        cross4(R1, R2, R3, c0);
        cross4(R0, R2, R3, c1);
        cross4(R0, R1, R3, c2);
        cross4(R0, R1, R2, c3);
        float n0 = c0[0]*c0[0] + c0[1]*c0[1] + c0[2]*c0[2] + c0[3]*c0[3];
        float n1 = c1[0]*c1[0] + c1[1]*c1[1] + c1[2]*c1[2] + c1[3]*c1[3];
        float n2 = c2[0]*c2[0] + c2[1]*c2[1] + c2[2]*c2[2] + c2[3]*c2[3];
        float n3 = c3[0]*c3[0] + c3[1]*c3[1] + c3[2]*c3[2] + c3[3]*c3[3];

        float bn = n0, w0 = c0[0], w1 = c0[1], w2 = c0[2], w3 = c0[3];
        bool b;
        b = n1 > bn; bn = b ? n1 : bn; w0 = b ? c1[0] : w0; w1 = b ? c1[1] : w1;
                     w2 = b ? c1[2] : w2; w3 = b ? c1[3] : w3;
        b = n2 > bn; bn = b ? n2 : bn; w0 = b ? c2[0] : w0; w1 = b ? c2[1] : w1;
                     w2 = b ? c2[2] : w2; w3 = b ? c2[3] : w3;
        b = n3 > bn; bn = b ? n3 : bn; w0 = b ? c3[0] : w0; w1 = b ? c3[1] : w1;
                     w2 = b ? c3[2] : w2; w3 = b ? c3[3] : w3;

        int i = tid + k * nthreads;
        int is = act[k] ? i : 0;
        float4 qt = *(const float4*)(q_t + (size_t)is * 4);
        float d = w0*qt.x + w1*qt.y + w2*qt.z + w3*qt.w;
        float inv = __builtin_amdgcn_rcpf(fmaxf(bn, 1e-20f));
        float loss = 8.f * (bn - d*d) * inv;
        loss = fminf(fmaxf(loss, 0.f), 8.f);
        lsum += act[k] ? loss : 0.f;
    }

    // ---- block reduction: wave64 shuffle -> LDS -> one atomic per block ---
    #pragma unroll
    for (int off = 32; off > 0; off >>= 1)
        lsum += __shfl_down(lsum, off, 64);
    __shared__ float sm[4];
    int lane = threadIdx.x & 63, wid = threadIdx.x >> 6;
    if (lane == 0) sm[wid] = lsum;
    __syncthreads();
    if (threadIdx.x == 0) {
        atomicAdd(acc, sm[0] + sm[1] + sm[2] + sm[3]);
        __threadfence();   // acc-add visible before cnt-add (device scope)
        unsigned int c = atomicAdd(cnt, 1u);
        if (c == (unsigned int)(nblocks - 1)) {
            float total = atomicAdd(acc, 0.f);  // atomic read: full sum
            out[0] = total / (float)B;
        }
    }
}

extern "C" void kernel_launch(void* const* d_in, const int* in_sizes, int n_in,
                              void* d_out, int out_size, void* d_ws, size_t ws_size,
                              hipStream_t stream)
{
    const float* A_vec = (const float*)d_in[0];
    const float* q_t   = (const float*)d_in[1];
    int B = in_sizes[0] / 10;
    float* acc = (float*)d_ws;
    unsigned int* cnt = (unsigned int*)((char*)d_ws + sizeof(float));

    hipMemsetAsync(d_ws, 0, 2 * sizeof(float), stream);
    int nthreads = (B + ILP - 1) / ILP;
    int nblocks = (nthreads + 255) / 256;
    qcqp_loss_kernel<<<nblocks, 256, 0, stream>>>(
        A_vec, q_t, acc, cnt, (float*)d_out, B, nthreads, nblocks);
}